// Round 9
// baseline (266.049 us; speedup 1.0000x reference)
//
#include <hip/hip_runtime.h>
#include <hip/hip_bf16.h>

#define DCH 64
#define NB_CSR 256          // CSR-build blocks; chunk = ceil(e/256)

typedef __attribute__((ext_vector_type(8))) short bfrag;   // 8 bf16
typedef __attribute__((ext_vector_type(4))) float ffrag;   // 4 fp32

static __device__ __forceinline__ unsigned short f2bf(float f) {
    unsigned u = __float_as_uint(f);
    unsigned r = (u + 0x7fffu + ((u >> 16) & 1u)) >> 16;   // RNE
    return (unsigned short)r;
}
static __device__ __forceinline__ float bf2f(unsigned short s) {
    return __uint_as_float(((unsigned)s) << 16);
}
// unpack 8 bf16 (uint4) -> 8 floats; q even = low u16, q odd = high u16
static __device__ __forceinline__ void unpack8(uint4 v, float f[8]) {
    f[0] = __uint_as_float(v.x << 16); f[1] = __uint_as_float(v.x & 0xffff0000u);
    f[2] = __uint_as_float(v.y << 16); f[3] = __uint_as_float(v.y & 0xffff0000u);
    f[4] = __uint_as_float(v.z << 16); f[5] = __uint_as_float(v.z & 0xffff0000u);
    f[6] = __uint_as_float(v.w << 16); f[7] = __uint_as_float(v.w & 0xffff0000u);
}

// ---- pass 1 (single edge pass): per-block LDS histogram, byte-packed bins ----
__global__ __launch_bounds__(1024) void histrank_k(const int* __restrict__ col,
                                                   unsigned char* __restrict__ hist,
                                                   unsigned char* __restrict__ lrank,
                                                   int n, int e) {
    __shared__ unsigned bins[12544];             // (n+3)/4 u32 byte-counters, ~50 KB
    int B = blockIdx.x, tid = threadIdx.x;
    int chunk = (e + NB_CSR - 1) / NB_CSR;
    int beg = B * chunk;
    int end = min(e, beg + chunk);
    int len = end - beg;
    int n4 = (n + 3) >> 2;
    for (int i = tid; i < n4; i += 1024) bins[i] = 0;
    __syncthreads();
    for (int i = tid; i < len; i += 1024) {
        int c = col[beg + i];
        unsigned sh = (c & 3) * 8;
        unsigned old = atomicAdd(&bins[c >> 2], 1u << sh);
        lrank[beg + i] = (unsigned char)((old >> sh) & 0xffu);
    }
    __syncthreads();
    unsigned* hrow32 = (unsigned*)(hist + (size_t)B * n);
    for (int i = tid; i < n4; i += 1024) hrow32[i] = bins[i];
}

// ---- pass 2: column-wise prefix over blocks (in place); cnt[b] = totals ----
__global__ __launch_bounds__(256) void hist2_k(unsigned char* __restrict__ hist,
                                               int* __restrict__ cnt, int n) {
    int g = blockIdx.x * 256 + threadIdx.x;     // 4-bin group
    int ng = n >> 2;
    if (g < ng) {
        unsigned r0 = 0, r1 = 0, r2 = 0, r3 = 0;
        size_t stride = (size_t)n >> 2;
        unsigned* p = (unsigned*)hist + g;
#pragma unroll 1
        for (int B = 0; B < NB_CSR; B += 4) {
            unsigned v0 = p[0], v1 = p[stride], v2 = p[2 * stride], v3 = p[3 * stride];
            p[0]          = (r0 & 255) | ((r1 & 255) << 8) | ((r2 & 255) << 16) | ((r3 & 255) << 24);
            r0 += v0 & 255; r1 += (v0 >> 8) & 255; r2 += (v0 >> 16) & 255; r3 += (v0 >> 24) & 255;
            p[stride]     = (r0 & 255) | ((r1 & 255) << 8) | ((r2 & 255) << 16) | ((r3 & 255) << 24);
            r0 += v1 & 255; r1 += (v1 >> 8) & 255; r2 += (v1 >> 16) & 255; r3 += (v1 >> 24) & 255;
            p[2 * stride] = (r0 & 255) | ((r1 & 255) << 8) | ((r2 & 255) << 16) | ((r3 & 255) << 24);
            r0 += v2 & 255; r1 += (v2 >> 8) & 255; r2 += (v2 >> 16) & 255; r3 += (v2 >> 24) & 255;
            p[3 * stride] = (r0 & 255) | ((r1 & 255) << 8) | ((r2 & 255) << 16) | ((r3 & 255) << 24);
            r0 += v3 & 255; r1 += (v3 >> 8) & 255; r2 += (v3 >> 16) & 255; r3 += (v3 >> 24) & 255;
            p += 4 * stride;
        }
        *(int4*)(cnt + 4 * g) = make_int4((int)r0, (int)r1, (int)r2, (int)r3);
    } else if (g == ng) {
        for (int b = ng << 2; b < n; ++b) {
            unsigned run = 0;
            for (int B = 0; B < NB_CSR; ++B) {
                unsigned char* p = hist + (size_t)B * n + b;
                unsigned v = *p; *p = (unsigned char)run; run += v;
            }
            cnt[b] = (int)run;
        }
    }
}

// ---- multi-block exclusive scan (3 phases; nb = ceil(n/1024) must be <= 64) ----
__global__ __launch_bounds__(1024) void scan1_k(const int* __restrict__ cnt,
                                                int* __restrict__ ptr,
                                                int* __restrict__ bsum, int n) {
    __shared__ int wtot[16];
    int tid = threadIdx.x, lane = tid & 63, w = tid >> 6;
    int i = blockIdx.x * 1024 + tid;
    int v = (i < n) ? cnt[i] : 0;
    int s = v;
#pragma unroll
    for (int off = 1; off < 64; off <<= 1) {
        int t = __shfl_up(s, off);
        if (lane >= off) s += t;
    }
    if (lane == 63) wtot[w] = s;
    __syncthreads();
    if (w == 0) {
        int t16 = (lane < 16) ? wtot[lane] : 0;
        int ss = t16;
#pragma unroll
        for (int off = 1; off < 16; off <<= 1) {
            int t = __shfl_up(ss, off);
            if (lane >= off) ss += t;
        }
        if (lane < 16) wtot[lane] = ss - t16;
    }
    __syncthreads();
    int excl = s - v + wtot[w];
    if (i < n) ptr[i] = excl;
    if (tid == 1023) bsum[blockIdx.x] = excl + v;
}

__global__ __launch_bounds__(64) void scan2_k(int* __restrict__ bsum, int nb) {
    int lane = threadIdx.x;
    int v = (lane < nb) ? bsum[lane] : 0;
    int s = v;
#pragma unroll
    for (int off = 1; off < 64; off <<= 1) {
        int t = __shfl_up(s, off);
        if (lane >= off) s += t;
    }
    if (lane < nb) bsum[lane] = s - v;
    if (lane == 63) bsum[nb] = s;
}

__global__ __launch_bounds__(1024) void scan3_k(int* __restrict__ ptr,
                                                const int* __restrict__ bsum,
                                                int n, int nb) {
    int i = blockIdx.x * 1024 + threadIdx.x;
    if (i < n) ptr[i] += bsum[blockIdx.x];
    if (i == 0) ptr[n] = bsum[nb];
}

// ---- pass 3: pure streaming placement ----
__global__ __launch_bounds__(256) void place_k(const int* __restrict__ row,
                                               const int* __restrict__ col,
                                               const float* __restrict__ ew,
                                               const int* __restrict__ ptr,
                                               const unsigned char* __restrict__ hist,
                                               const unsigned char* __restrict__ lrank,
                                               uint2* __restrict__ edg,
                                               int chunk, int n, int e) {
    int i = blockIdx.x * 256 + threadIdx.x;
    if (i >= e) return;
    int B = i / chunk;
    int c = col[i];
    int p = ptr[c] + (int)hist[(size_t)B * n + c] + (int)lrank[i];
    edg[p] = make_uint2((unsigned)row[i], __float_as_uint(ew[i]));
}

// dis[c] = rsqrt(sum_bucket(w) + 2.0)
__global__ __launch_bounds__(256) void deg_k(const int* __restrict__ ptr,
                                             const uint2* __restrict__ edg,
                                             float* __restrict__ dis, int n) {
    int node = blockIdx.x * 4 + (threadIdx.x >> 6);
    int lane = threadIdx.x & 63;
    if (node >= n) return;
    int beg = ptr[node], end = ptr[node + 1];
    float s = 0.f;
    for (int p = beg + lane; p < end; p += 64) s += __uint_as_float(edg[p].y);
#pragma unroll
    for (int off = 32; off > 0; off >>= 1) s += __shfl_down(s, off);
    if (lane == 0) dis[node] = rsqrtf(s + 2.0f);
}

// edg.y <- w * dis[src]  (fold source-side norm in once, for all layers)
__global__ __launch_bounds__(256) void normw_k(uint2* __restrict__ edg,
                                               const float* __restrict__ dis, int e) {
    int i = blockIdx.x * 256 + threadIdx.x;
    if (i >= e) return;
    uint2 ev = edg[i];
    ((unsigned*)edg)[2 * i + 1] =
        __float_as_uint(__uint_as_float(ev.y) * dis[ev.x]);
}

// Pack W (all L layers) into MFMA B-fragment layout, bf16 hi/lo split.
__global__ __launch_bounds__(256) void pack_k(const float* __restrict__ Ws,
                                              short* __restrict__ wpk, int L) {
    int ent = blockIdx.x * 256 + threadIdx.x;
    if (ent >= L * 512) return;
    int layer = ent >> 9;
    int r = ent & 511;
    int lane = r & 63;
    int st = r >> 6;
    int s = st >> 2, t = st & 3;
    int quad = lane >> 4;
    int ncol = t * 16 + (lane & 15);
    const float* W = Ws + (size_t)layer * DCH * DCH;
    union { short sh[8]; int4 v; } hi, lo;
#pragma unroll
    for (int j = 0; j < 8; ++j) {
        int k = s * 32 + quad * 8 + j;
        float w = W[k * DCH + ncol];
        unsigned short h = f2bf(w);
        hi.sh[j] = (short)h;
        lo.sh[j] = (short)f2bf(w - bf2f(h));
    }
    *(int4*)(wpk + ((size_t)(layer * 2 + 0) * 512 + r) * 8) = hi.v;
    *(int4*)(wpk + ((size_t)(layer * 2 + 1) * 512 + r) * 8) = lo.v;
}

// layer-0 GEMM: h = x0 @ W0 via bf16-split MFMA; output bf16.
__global__ __launch_bounds__(256) void gemm_k(const float* __restrict__ x,
                                              const short* __restrict__ wpk_layer,
                                              unsigned short* __restrict__ hb, int n_tiles) {
    __shared__ short Wl[2][512 * 8];
    {
        const int4* src = (const int4*)wpk_layer;
        int4* dst = (int4*)&Wl[0][0];
        for (int i = threadIdx.x; i < 1024; i += 256) dst[i] = src[i];
    }
    __syncthreads();
    int wave = threadIdx.x >> 6, lane = threadIdx.x & 63;
    int tile = blockIdx.x * 4 + wave;
    if (tile >= n_tiles) return;
    int m = lane & 15, quad = lane >> 4;
    int row = tile * 16 + m;

    float av[2][8];
    {
        const float4* p0 = (const float4*)(x + (size_t)row * DCH + quad * 8);
        const float4* p1 = (const float4*)(x + (size_t)row * DCH + 32 + quad * 8);
        float4 a0 = p0[0], a1 = p0[1], b0 = p1[0], b1 = p1[1];
        av[0][0] = a0.x; av[0][1] = a0.y; av[0][2] = a0.z; av[0][3] = a0.w;
        av[0][4] = a1.x; av[0][5] = a1.y; av[0][6] = a1.z; av[0][7] = a1.w;
        av[1][0] = b0.x; av[1][1] = b0.y; av[1][2] = b0.z; av[1][3] = b0.w;
        av[1][4] = b1.x; av[1][5] = b1.y; av[1][6] = b1.z; av[1][7] = b1.w;
    }
    bfrag ah[2], al[2];
#pragma unroll
    for (int s = 0; s < 2; ++s)
#pragma unroll
        for (int j = 0; j < 8; ++j) {
            unsigned short hbv = f2bf(av[s][j]);
            ah[s][j] = (short)hbv;
            al[s][j] = (short)f2bf(av[s][j] - bf2f(hbv));
        }

#pragma unroll
    for (int t = 0; t < 4; ++t) {
        ffrag acc = {0.f, 0.f, 0.f, 0.f};
#pragma unroll
        for (int s = 0; s < 2; ++s) {
            bfrag wh = *(bfrag*)&Wl[0][((s * 4 + t) * 64 + lane) * 8];
            bfrag wl = *(bfrag*)&Wl[1][((s * 4 + t) * 64 + lane) * 8];
            acc = __builtin_amdgcn_mfma_f32_16x16x32_bf16(ah[s], wh, acc, 0, 0, 0);
            acc = __builtin_amdgcn_mfma_f32_16x16x32_bf16(al[s], wh, acc, 0, 0, 0);
            acc = __builtin_amdgcn_mfma_f32_16x16x32_bf16(ah[s], wl, acc, 0, 0, 0);
        }
        int colc = t * 16 + m;
#pragma unroll
        for (int r = 0; r < 4; ++r)
            hb[(size_t)(tile * 16 + quad * 4 + r) * DCH + colc] = f2bf(acc[r]);
    }
}

// gather core, 16B loads: 8 lanes per edge row (lane sub = channel octet),
// 8 edges per step, 2-step unrolled. After the grp-merge, ALL lanes hold the
// node's 64-channel aggregate as acc[8] for channels sub*8..sub*8+7.
static __device__ __forceinline__ void gather_node16(int node, int lane, int sub, int grp,
                                                     float dis_c,
                                                     const int* __restrict__ ptr,
                                                     const uint2* __restrict__ edg,
                                                     const uint4* __restrict__ hb4,
                                                     float acc[8]) {
    if (grp == 0) {                              // self-loop term (once)
        float f[8];
        unpack8(hb4[(size_t)node * 8 + sub], f);
#pragma unroll
        for (int q = 0; q < 8; ++q) acc[q] = 2.0f * dis_c * f[q];
    } else {
#pragma unroll
        for (int q = 0; q < 8; ++q) acc[q] = 0.f;
    }
    int beg = ptr[node], end = ptr[node + 1];
    for (int base = beg; base < end; base += 64) {
        int idx = base + lane;
        int rv = 0; float nv = 0.f;
        if (idx < end) {
            uint2 ev = edg[idx];
            rv = (int)ev.x;
            nv = __uint_as_float(ev.y);          // pre-folded w * dis[src]
        }
        int m = min(64, end - base);
        int ns2 = (((m + 7) >> 3) + 1) & ~1;     // steps of 8 edges, 2-unrolled
        for (int s = 0; s < ns2; s += 2) {
            int e0 = s * 8 + grp, e1 = e0 + 8;   // padded lanes carry nv=0
            int   r0 = __shfl(rv, e0);
            float n0 = __shfl(nv, e0);
            int   r1 = __shfl(rv, e1);
            float n1 = __shfl(nv, e1);
            uint4 h0 = hb4[(size_t)r0 * 8 + sub];
            uint4 h1 = hb4[(size_t)r1 * 8 + sub];
            float f0[8], f1[8];
            unpack8(h0, f0); unpack8(h1, f1);
#pragma unroll
            for (int q = 0; q < 8; ++q) acc[q] += f0[q] * n0 + f1[q] * n1;
        }
    }
#pragma unroll
    for (int q = 0; q < 8; ++q) {                // merge the 8 edge-groups
        acc[q] += __shfl_xor(acc[q], 8);
        acc[q] += __shfl_xor(acc[q], 16);
        acc[q] += __shfl_xor(acc[q], 32);
    }
}

// fused gather(l) + gemm(l+1): block = 4 waves = 16 nodes; activation tile in
// LDS (stride 68: 16B-aligned rows); wave t does MFMA col-group t.
__global__ __launch_bounds__(256) void gg_k(const int* __restrict__ ptr,
                                            const uint2* __restrict__ edg,
                                            const float* __restrict__ dis,
                                            const uint4* __restrict__ hb4,
                                            const float* __restrict__ b,
                                            const short* __restrict__ wpk_next,
                                            unsigned short* __restrict__ hb_out, int n) {
    __shared__ float xs[16][68];
    int w = threadIdx.x >> 6, lane = threadIdx.x & 63;
    int sub = lane & 7, grp = lane >> 3;
    int tile = blockIdx.x;
    float4 b0 = ((const float4*)b)[sub * 2];
    float4 b1 = ((const float4*)b)[sub * 2 + 1];
#pragma unroll 1
    for (int i = 0; i < 4; ++i) {
        int node = tile * 16 + w * 4 + i;
        if (node < n) {
            float dis_c = dis[node];
            float acc[8];
            gather_node16(node, lane, sub, grp, dis_c, ptr, edg, hb4, acc);
            if (grp == 0) {
                float4 r0, r1;
                r0.x = fmaxf(dis_c * acc[0] + b0.x, 0.f);
                r0.y = fmaxf(dis_c * acc[1] + b0.y, 0.f);
                r0.z = fmaxf(dis_c * acc[2] + b0.z, 0.f);
                r0.w = fmaxf(dis_c * acc[3] + b0.w, 0.f);
                r1.x = fmaxf(dis_c * acc[4] + b1.x, 0.f);
                r1.y = fmaxf(dis_c * acc[5] + b1.y, 0.f);
                r1.z = fmaxf(dis_c * acc[6] + b1.z, 0.f);
                r1.w = fmaxf(dis_c * acc[7] + b1.w, 0.f);
                *(float4*)&xs[w * 4 + i][sub * 8]     = r0;
                *(float4*)&xs[w * 4 + i][sub * 8 + 4] = r1;
            }
        }
    }
    __syncthreads();
    // ---- GEMM phase: wave w = output col-group t ----
    int m = lane & 15, quad = lane >> 4, t = w;
    bfrag ah[2], al[2];
#pragma unroll
    for (int s = 0; s < 2; ++s)
#pragma unroll
        for (int j = 0; j < 8; ++j) {
            float v = xs[m][s * 32 + quad * 8 + j];
            unsigned short hbv = f2bf(v);
            ah[s][j] = (short)hbv;
            al[s][j] = (short)f2bf(v - bf2f(hbv));
        }
    ffrag acc = {0.f, 0.f, 0.f, 0.f};
#pragma unroll
    for (int s = 0; s < 2; ++s) {
        bfrag wh = *(const bfrag*)(wpk_next + ((size_t)((s * 4 + t) * 64 + lane)) * 8);
        bfrag wl = *(const bfrag*)(wpk_next + ((size_t)(512 + (s * 4 + t) * 64 + lane)) * 8);
        acc = __builtin_amdgcn_mfma_f32_16x16x32_bf16(ah[s], wh, acc, 0, 0, 0);
        acc = __builtin_amdgcn_mfma_f32_16x16x32_bf16(al[s], wh, acc, 0, 0, 0);
        acc = __builtin_amdgcn_mfma_f32_16x16x32_bf16(ah[s], wl, acc, 0, 0, 0);
    }
    int colc = t * 16 + m;
#pragma unroll
    for (int r = 0; r < 4; ++r) {
        int orow = tile * 16 + quad * 4 + r;
        if (orow < n) hb_out[(size_t)orow * DCH + colc] = f2bf(acc[r]);
    }
}

// fused gather(last) + final dot: out[node] = relu-agg(node) . Wf + bf
__global__ __launch_bounds__(256) void gf_k(const int* __restrict__ ptr,
                                            const uint2* __restrict__ edg,
                                            const float* __restrict__ dis,
                                            const uint4* __restrict__ hb4,
                                            const float* __restrict__ b,
                                            const float* __restrict__ Wf,
                                            const float* __restrict__ bf,
                                            float* __restrict__ out, int n) {
    int node = blockIdx.x * 4 + (threadIdx.x >> 6);
    int lane = threadIdx.x & 63;
    if (node >= n) return;
    int sub = lane & 7, grp = lane >> 3;
    float dis_c = dis[node];
    float acc[8];
    gather_node16(node, lane, sub, grp, dis_c, ptr, edg, hb4, acc);
    float v = 0.f;
    if (grp == 0) {
        float4 b0 = ((const float4*)b)[sub * 2];
        float4 b1 = ((const float4*)b)[sub * 2 + 1];
        float4 w0 = ((const float4*)Wf)[sub * 2];
        float4 w1 = ((const float4*)Wf)[sub * 2 + 1];
        v  = fmaxf(dis_c * acc[0] + b0.x, 0.f) * w0.x;
        v += fmaxf(dis_c * acc[1] + b0.y, 0.f) * w0.y;
        v += fmaxf(dis_c * acc[2] + b0.z, 0.f) * w0.z;
        v += fmaxf(dis_c * acc[3] + b0.w, 0.f) * w0.w;
        v += fmaxf(dis_c * acc[4] + b1.x, 0.f) * w1.x;
        v += fmaxf(dis_c * acc[5] + b1.y, 0.f) * w1.y;
        v += fmaxf(dis_c * acc[6] + b1.z, 0.f) * w1.z;
        v += fmaxf(dis_c * acc[7] + b1.w, 0.f) * w1.w;
    }
    v += __shfl_down(v, 4);                      // reduce lanes 0..7
    v += __shfl_down(v, 2);
    v += __shfl_down(v, 1);
    if (lane == 0) out[node] = v + bf[0];
}

extern "C" void kernel_launch(void* const* d_in, const int* in_sizes, int n_in,
                              void* d_out, int out_size, void* d_ws, size_t ws_size,
                              hipStream_t stream) {
    const float* x0 = (const float*)d_in[0];
    const int*   ei = (const int*)d_in[1];
    const float* ew = (const float*)d_in[2];
    const float* Ws = (const float*)d_in[3];
    const float* bs = (const float*)d_in[4];
    const float* Wf = (const float*)d_in[5];
    const float* bf = (const float*)d_in[6];

    const int n = in_sizes[0] / DCH;
    const int e = in_sizes[2];
    const int L = in_sizes[3] / (DCH * DCH);     // = 3

    const int* row = ei;        // edge_index[0] = source (gathered)
    const int* col = ei + e;    // edge_index[1] = target (aggregated)

    size_t off = 0;
    auto alloc = [&](size_t bytes) {
        off = (off + 255) & ~(size_t)255;
        void* r = (char*)d_ws + off;
        off += bytes;
        return r;
    };
    const int nb_scan = (n + 1023) / 1024;       // must be <= 64
    int*   cnt  = (int*)  alloc((size_t)n * 4);
    int*   ptr  = (int*)  alloc((size_t)(n + 1) * 4);
    int*   bsum = (int*)  alloc((size_t)(nb_scan + 1) * 4);
    float* dis  = (float*)alloc((size_t)n * 4);
    short* wpk  = (short*)alloc((size_t)L * 2 * 512 * 8 * 2);
    uint2* edg  = (uint2*)alloc((size_t)e * 8);
    unsigned char* lrank = (unsigned char*)alloc((size_t)e);
    // region A: hist (NB_CSR*n u8) aliases TWO bf16 h buffers (2*n*64*2 bytes);
    // hist is dead after place_k, which precedes the first gemm write.
    size_t szA = (size_t)NB_CSR * n;
    size_t szH = (size_t)2 * n * DCH * 2;
    unsigned char* hist = (unsigned char*)alloc(szA > szH ? szA : szH);
    unsigned short* hb_a = (unsigned short*)hist;
    unsigned short* hb_b = hb_a + (size_t)n * DCH;

    dim3 blk(256);
    const int n_tiles = (n + 15) / 16;
    const int chunk = (e + NB_CSR - 1) / NB_CSR;

    // ---- CSR build + norm + W pack ----
    histrank_k<<<dim3(NB_CSR), dim3(1024), 0, stream>>>(col, hist, lrank, n, e);
    hist2_k   <<<dim3((n / 4 + 1 + 255) / 256), blk, 0, stream>>>(hist, cnt, n);
    scan1_k   <<<dim3(nb_scan), dim3(1024), 0, stream>>>(cnt, ptr, bsum, n);
    scan2_k   <<<dim3(1), dim3(64), 0, stream>>>(bsum, nb_scan);
    scan3_k   <<<dim3(nb_scan), dim3(1024), 0, stream>>>(ptr, bsum, n, nb_scan);
    place_k   <<<dim3((e + 255) / 256), blk, 0, stream>>>(row, col, ew, ptr, hist, lrank, edg, chunk, n, e);
    deg_k     <<<dim3((n + 3) / 4), blk, 0, stream>>>(ptr, edg, dis, n);
    normw_k   <<<dim3((e + 255) / 256), blk, 0, stream>>>(edg, dis, e);
    pack_k    <<<dim3((L * 512 + 255) / 256), blk, 0, stream>>>(Ws, wpk, L);

    // ---- layers (fused) ----
    const size_t wstride = (size_t)2 * 512 * 8;
    gemm_k<<<dim3((n_tiles + 3) / 4), blk, 0, stream>>>(x0, wpk, hb_a, n_tiles);
    gg_k  <<<dim3(n_tiles), blk, 0, stream>>>(ptr, edg, dis, (const uint4*)hb_a,
                                              bs, wpk + wstride, hb_b, n);
    gg_k  <<<dim3(n_tiles), blk, 0, stream>>>(ptr, edg, dis, (const uint4*)hb_b,
                                              bs + DCH, wpk + 2 * wstride, hb_a, n);
    gf_k  <<<dim3((n + 3) / 4), blk, 0, stream>>>(ptr, edg, dis, (const uint4*)hb_a,
                                                  bs + 2 * DCH, Wf, bf, (float*)d_out, n);
}

// Round 10
// 254.732 us; speedup vs baseline: 1.0444x; 1.0444x over previous
//
#include <hip/hip_runtime.h>
#include <hip/hip_bf16.h>

#define DCH 64
#define NB_CSR 256          // CSR-build blocks; chunk = ceil(e/256)

typedef __attribute__((ext_vector_type(8))) short bfrag;   // 8 bf16
typedef __attribute__((ext_vector_type(4))) float ffrag;   // 4 fp32

static __device__ __forceinline__ unsigned short f2bf(float f) {
    unsigned u = __float_as_uint(f);
    unsigned r = (u + 0x7fffu + ((u >> 16) & 1u)) >> 16;   // RNE
    return (unsigned short)r;
}
static __device__ __forceinline__ float bf2f(unsigned short s) {
    return __uint_as_float(((unsigned)s) << 16);
}

// ---- pass 1 (single edge pass): per-block LDS histogram, byte-packed bins ----
__global__ __launch_bounds__(1024) void histrank_k(const int* __restrict__ col,
                                                   unsigned char* __restrict__ hist,
                                                   unsigned char* __restrict__ lrank,
                                                   int n, int e) {
    __shared__ unsigned bins[12544];             // (n+3)/4 u32 byte-counters, ~50 KB
    int B = blockIdx.x, tid = threadIdx.x;
    int chunk = (e + NB_CSR - 1) / NB_CSR;
    int beg = B * chunk;
    int end = min(e, beg + chunk);
    int len = end - beg;
    int n4 = (n + 3) >> 2;
    for (int i = tid; i < n4; i += 1024) bins[i] = 0;
    __syncthreads();
    for (int i = tid; i < len; i += 1024) {
        int c = col[beg + i];
        unsigned sh = (c & 3) * 8;
        unsigned old = atomicAdd(&bins[c >> 2], 1u << sh);
        lrank[beg + i] = (unsigned char)((old >> sh) & 0xffu);
    }
    __syncthreads();
    unsigned* hrow32 = (unsigned*)(hist + (size_t)B * n);
    for (int i = tid; i < n4; i += 1024) hrow32[i] = bins[i];
}

// ---- pass 2: column-wise prefix over blocks (in place); cnt[b] = totals ----
__global__ __launch_bounds__(256) void hist2_k(unsigned char* __restrict__ hist,
                                               int* __restrict__ cnt, int n) {
    int g = blockIdx.x * 256 + threadIdx.x;     // 4-bin group
    int ng = n >> 2;
    if (g < ng) {
        unsigned r0 = 0, r1 = 0, r2 = 0, r3 = 0;
        size_t stride = (size_t)n >> 2;
        unsigned* p = (unsigned*)hist + g;
#pragma unroll 1
        for (int B = 0; B < NB_CSR; B += 4) {
            unsigned v0 = p[0], v1 = p[stride], v2 = p[2 * stride], v3 = p[3 * stride];
            p[0]          = (r0 & 255) | ((r1 & 255) << 8) | ((r2 & 255) << 16) | ((r3 & 255) << 24);
            r0 += v0 & 255; r1 += (v0 >> 8) & 255; r2 += (v0 >> 16) & 255; r3 += (v0 >> 24) & 255;
            p[stride]     = (r0 & 255) | ((r1 & 255) << 8) | ((r2 & 255) << 16) | ((r3 & 255) << 24);
            r0 += v1 & 255; r1 += (v1 >> 8) & 255; r2 += (v1 >> 16) & 255; r3 += (v1 >> 24) & 255;
            p[2 * stride] = (r0 & 255) | ((r1 & 255) << 8) | ((r2 & 255) << 16) | ((r3 & 255) << 24);
            r0 += v2 & 255; r1 += (v2 >> 8) & 255; r2 += (v2 >> 16) & 255; r3 += (v2 >> 24) & 255;
            p[3 * stride] = (r0 & 255) | ((r1 & 255) << 8) | ((r2 & 255) << 16) | ((r3 & 255) << 24);
            r0 += v3 & 255; r1 += (v3 >> 8) & 255; r2 += (v3 >> 16) & 255; r3 += (v3 >> 24) & 255;
            p += 4 * stride;
        }
        *(int4*)(cnt + 4 * g) = make_int4((int)r0, (int)r1, (int)r2, (int)r3);
    } else if (g == ng) {
        for (int b = ng << 2; b < n; ++b) {
            unsigned run = 0;
            for (int B = 0; B < NB_CSR; ++B) {
                unsigned char* p = hist + (size_t)B * n + b;
                unsigned v = *p; *p = (unsigned char)run; run += v;
            }
            cnt[b] = (int)run;
        }
    }
}

// ---- multi-block exclusive scan (3 phases; nb = ceil(n/1024) must be <= 64) ----
__global__ __launch_bounds__(1024) void scan1_k(const int* __restrict__ cnt,
                                                int* __restrict__ ptr,
                                                int* __restrict__ bsum, int n) {
    __shared__ int wtot[16];
    int tid = threadIdx.x, lane = tid & 63, w = tid >> 6;
    int i = blockIdx.x * 1024 + tid;
    int v = (i < n) ? cnt[i] : 0;
    int s = v;
#pragma unroll
    for (int off = 1; off < 64; off <<= 1) {
        int t = __shfl_up(s, off);
        if (lane >= off) s += t;
    }
    if (lane == 63) wtot[w] = s;
    __syncthreads();
    if (w == 0) {
        int t16 = (lane < 16) ? wtot[lane] : 0;
        int ss = t16;
#pragma unroll
        for (int off = 1; off < 16; off <<= 1) {
            int t = __shfl_up(ss, off);
            if (lane >= off) ss += t;
        }
        if (lane < 16) wtot[lane] = ss - t16;
    }
    __syncthreads();
    int excl = s - v + wtot[w];
    if (i < n) ptr[i] = excl;
    if (tid == 1023) bsum[blockIdx.x] = excl + v;
}

__global__ __launch_bounds__(64) void scan2_k(int* __restrict__ bsum, int nb) {
    int lane = threadIdx.x;
    int v = (lane < nb) ? bsum[lane] : 0;
    int s = v;
#pragma unroll
    for (int off = 1; off < 64; off <<= 1) {
        int t = __shfl_up(s, off);
        if (lane >= off) s += t;
    }
    if (lane < nb) bsum[lane] = s - v;
    if (lane == 63) bsum[nb] = s;
}

__global__ __launch_bounds__(1024) void scan3_k(int* __restrict__ ptr,
                                                const int* __restrict__ bsum,
                                                int n, int nb) {
    int i = blockIdx.x * 1024 + threadIdx.x;
    if (i < n) ptr[i] += bsum[blockIdx.x];
    if (i == 0) ptr[n] = bsum[nb];
}

// ---- pass 3: placement with LDS-staged hist row (block B <-> chunk B) ----
__global__ __launch_bounds__(1024) void place_k(const int* __restrict__ row,
                                                const int* __restrict__ col,
                                                const float* __restrict__ ew,
                                                const int* __restrict__ ptr,
                                                const unsigned char* __restrict__ hist,
                                                const unsigned char* __restrict__ lrank,
                                                uint2* __restrict__ edg,
                                                int n, int e) {
    __shared__ unsigned hrow_s[12544];           // this block's hist row (u8, packed)
    int B = blockIdx.x, tid = threadIdx.x;
    int chunk = (e + NB_CSR - 1) / NB_CSR;
    int beg = B * chunk;
    int end = min(e, beg + chunk);
    int n4 = (n + 3) >> 2;
    const unsigned* hrow32 = (const unsigned*)(hist + (size_t)B * n);
    for (int i = tid; i < n4; i += 1024) hrow_s[i] = hrow32[i];   // streaming copy
    __syncthreads();
    const unsigned char* hrow8 = (const unsigned char*)hrow_s;
    for (int i = beg + tid; i < end; i += 1024) {
        int c = col[i];
        int p = ptr[c] + (int)hrow8[c] + (int)lrank[i];
        edg[p] = make_uint2((unsigned)row[i], __float_as_uint(ew[i]));
    }
}

// dis[c] = rsqrt(sum_bucket(w) + 2.0)
__global__ __launch_bounds__(256) void deg_k(const int* __restrict__ ptr,
                                             const uint2* __restrict__ edg,
                                             float* __restrict__ dis, int n) {
    int node = blockIdx.x * 4 + (threadIdx.x >> 6);
    int lane = threadIdx.x & 63;
    if (node >= n) return;
    int beg = ptr[node], end = ptr[node + 1];
    float s = 0.f;
    for (int p = beg + lane; p < end; p += 64) s += __uint_as_float(edg[p].y);
#pragma unroll
    for (int off = 32; off > 0; off >>= 1) s += __shfl_down(s, off);
    if (lane == 0) dis[node] = rsqrtf(s + 2.0f);
}

// edg.y <- w * dis[src]  (fold source-side norm in once, for all layers)
__global__ __launch_bounds__(256) void normw_k(uint2* __restrict__ edg,
                                               const float* __restrict__ dis, int e) {
    int i = blockIdx.x * 256 + threadIdx.x;
    if (i >= e) return;
    uint2 ev = edg[i];
    ((unsigned*)edg)[2 * i + 1] =
        __float_as_uint(__uint_as_float(ev.y) * dis[ev.x]);
}

// Pack W (all L layers) into MFMA B-fragment layout, bf16 hi/lo split.
__global__ __launch_bounds__(256) void pack_k(const float* __restrict__ Ws,
                                              short* __restrict__ wpk, int L) {
    int ent = blockIdx.x * 256 + threadIdx.x;
    if (ent >= L * 512) return;
    int layer = ent >> 9;
    int r = ent & 511;
    int lane = r & 63;
    int st = r >> 6;
    int s = st >> 2, t = st & 3;
    int quad = lane >> 4;
    int ncol = t * 16 + (lane & 15);
    const float* W = Ws + (size_t)layer * DCH * DCH;
    union { short sh[8]; int4 v; } hi, lo;
#pragma unroll
    for (int j = 0; j < 8; ++j) {
        int k = s * 32 + quad * 8 + j;
        float w = W[k * DCH + ncol];
        unsigned short h = f2bf(w);
        hi.sh[j] = (short)h;
        lo.sh[j] = (short)f2bf(w - bf2f(h));
    }
    *(int4*)(wpk + ((size_t)(layer * 2 + 0) * 512 + r) * 8) = hi.v;
    *(int4*)(wpk + ((size_t)(layer * 2 + 1) * 512 + r) * 8) = lo.v;
}

// layer-0 GEMM: h = x0 @ W0 via bf16-split MFMA; output bf16.
__global__ __launch_bounds__(256) void gemm_k(const float* __restrict__ x,
                                              const short* __restrict__ wpk_layer,
                                              unsigned short* __restrict__ hb, int n_tiles) {
    __shared__ short Wl[2][512 * 8];
    {
        const int4* src = (const int4*)wpk_layer;
        int4* dst = (int4*)&Wl[0][0];
        for (int i = threadIdx.x; i < 1024; i += 256) dst[i] = src[i];
    }
    __syncthreads();
    int wave = threadIdx.x >> 6, lane = threadIdx.x & 63;
    int tile = blockIdx.x * 4 + wave;
    if (tile >= n_tiles) return;
    int m = lane & 15, quad = lane >> 4;
    int row = tile * 16 + m;

    float av[2][8];
    {
        const float4* p0 = (const float4*)(x + (size_t)row * DCH + quad * 8);
        const float4* p1 = (const float4*)(x + (size_t)row * DCH + 32 + quad * 8);
        float4 a0 = p0[0], a1 = p0[1], b0 = p1[0], b1 = p1[1];
        av[0][0] = a0.x; av[0][1] = a0.y; av[0][2] = a0.z; av[0][3] = a0.w;
        av[0][4] = a1.x; av[0][5] = a1.y; av[0][6] = a1.z; av[0][7] = a1.w;
        av[1][0] = b0.x; av[1][1] = b0.y; av[1][2] = b0.z; av[1][3] = b0.w;
        av[1][4] = b1.x; av[1][5] = b1.y; av[1][6] = b1.z; av[1][7] = b1.w;
    }
    bfrag ah[2], al[2];
#pragma unroll
    for (int s = 0; s < 2; ++s)
#pragma unroll
        for (int j = 0; j < 8; ++j) {
            unsigned short hbv = f2bf(av[s][j]);
            ah[s][j] = (short)hbv;
            al[s][j] = (short)f2bf(av[s][j] - bf2f(hbv));
        }

#pragma unroll
    for (int t = 0; t < 4; ++t) {
        ffrag acc = {0.f, 0.f, 0.f, 0.f};
#pragma unroll
        for (int s = 0; s < 2; ++s) {
            bfrag wh = *(bfrag*)&Wl[0][((s * 4 + t) * 64 + lane) * 8];
            bfrag wl = *(bfrag*)&Wl[1][((s * 4 + t) * 64 + lane) * 8];
            acc = __builtin_amdgcn_mfma_f32_16x16x32_bf16(ah[s], wh, acc, 0, 0, 0);
            acc = __builtin_amdgcn_mfma_f32_16x16x32_bf16(al[s], wh, acc, 0, 0, 0);
            acc = __builtin_amdgcn_mfma_f32_16x16x32_bf16(ah[s], wl, acc, 0, 0, 0);
        }
        int colc = t * 16 + m;
#pragma unroll
        for (int r = 0; r < 4; ++r)
            hb[(size_t)(tile * 16 + quad * 4 + r) * DCH + colc] = f2bf(acc[r]);
    }
}

// gather core (R7 version): lane = channel pair, 2 edges/step, 8-deep pipelined.
// 8 outstanding 4B loads per lane — max MLP for this latency-bound loop.
static __device__ __forceinline__ void gather_node(int node, int lane, int p, int hf,
                                                   float dis_c,
                                                   const int* __restrict__ ptr,
                                                   const uint2* __restrict__ edg,
                                                   const unsigned* __restrict__ hbf,
                                                   float& A0, float& A1) {
    float a0 = 0.f, a1 = 0.f;
    if (hf == 0) {                               // self-loop term
        unsigned sv = hbf[(size_t)node * 32 + p];
        a0 = 2.0f * dis_c * __uint_as_float(sv << 16);
        a1 = 2.0f * dis_c * __uint_as_float(sv & 0xffff0000u);
    }
    int beg = ptr[node], end = ptr[node + 1];
    for (int base = beg; base < end; base += 64) {
        int idx = base + lane;
        int rv = 0; float nv = 0.f;
        if (idx < end) {
            uint2 ev = edg[idx];
            rv = (int)ev.x;
            nv = __uint_as_float(ev.y);          // pre-folded w * dis[src]
        }
        int m = min(64, end - base);
        int steps = (((m + 1) >> 1) + 7) & ~7;   // 2 edges/step, 8-deep pipelined
        for (int j0 = 0; j0 < steps; j0 += 8) {
            unsigned hv[8]; float nn[8];
#pragma unroll
            for (int q = 0; q < 8; ++q) {
                int eidx = 2 * (j0 + q) + hf;
                int r = __shfl(rv, eidx);
                nn[q] = __shfl(nv, eidx);
                hv[q] = hbf[(size_t)r * 32 + p];
            }
#pragma unroll
            for (int q = 0; q < 8; ++q) {
                a0 += __uint_as_float(hv[q] << 16) * nn[q];
                a1 += __uint_as_float(hv[q] & 0xffff0000u) * nn[q];
            }
        }
    }
    A0 = a0 + __shfl_xor(a0, 32);
    A1 = a1 + __shfl_xor(a1, 32);
}

// fused gather(l) + gemm(l+1): block = 4 waves = 16 nodes; activation tile in
// LDS (stride 68: 16B-aligned rows); wave t does MFMA col-group t.
__global__ __launch_bounds__(256) void gg_k(const int* __restrict__ ptr,
                                            const uint2* __restrict__ edg,
                                            const float* __restrict__ dis,
                                            const unsigned* __restrict__ hbf,
                                            const float* __restrict__ b,
                                            const short* __restrict__ wpk_next,
                                            unsigned short* __restrict__ hb_out, int n) {
    __shared__ float xs[16][68];
    int w = threadIdx.x >> 6, lane = threadIdx.x & 63;
    int p = lane & 31, hf = lane >> 5;
    int tile = blockIdx.x;
    float2 bv = ((const float2*)b)[p];
#pragma unroll 1
    for (int i = 0; i < 4; ++i) {
        int node = tile * 16 + w * 4 + i;
        if (node < n) {
            float dis_c = dis[node];
            float A0, A1;
            gather_node(node, lane, p, hf, dis_c, ptr, edg, hbf, A0, A1);
            if (hf == 0) {
                xs[w * 4 + i][2 * p]     = fmaxf(dis_c * A0 + bv.x, 0.f);
                xs[w * 4 + i][2 * p + 1] = fmaxf(dis_c * A1 + bv.y, 0.f);
            }
        }
    }
    __syncthreads();
    // ---- GEMM phase: wave w = output col-group t ----
    int m = lane & 15, quad = lane >> 4, t = w;
    bfrag ah[2], al[2];
#pragma unroll
    for (int s = 0; s < 2; ++s)
#pragma unroll
        for (int j = 0; j < 8; ++j) {
            float v = xs[m][s * 32 + quad * 8 + j];
            unsigned short hbv = f2bf(v);
            ah[s][j] = (short)hbv;
            al[s][j] = (short)f2bf(v - bf2f(hbv));
        }
    ffrag acc = {0.f, 0.f, 0.f, 0.f};
#pragma unroll
    for (int s = 0; s < 2; ++s) {
        bfrag wh = *(const bfrag*)(wpk_next + ((size_t)((s * 4 + t) * 64 + lane)) * 8);
        bfrag wl = *(const bfrag*)(wpk_next + ((size_t)(512 + (s * 4 + t) * 64 + lane)) * 8);
        acc = __builtin_amdgcn_mfma_f32_16x16x32_bf16(ah[s], wh, acc, 0, 0, 0);
        acc = __builtin_amdgcn_mfma_f32_16x16x32_bf16(al[s], wh, acc, 0, 0, 0);
        acc = __builtin_amdgcn_mfma_f32_16x16x32_bf16(ah[s], wl, acc, 0, 0, 0);
    }
    int colc = t * 16 + m;
#pragma unroll
    for (int r = 0; r < 4; ++r) {
        int orow = tile * 16 + quad * 4 + r;
        if (orow < n) hb_out[(size_t)orow * DCH + colc] = f2bf(acc[r]);
    }
}

// fused gather(last) + final dot: out[node] = relu-agg(node) . Wf + bf
__global__ __launch_bounds__(256) void gf_k(const int* __restrict__ ptr,
                                            const uint2* __restrict__ edg,
                                            const float* __restrict__ dis,
                                            const unsigned* __restrict__ hbf,
                                            const float* __restrict__ b,
                                            const float* __restrict__ Wf,
                                            const float* __restrict__ bf,
                                            float* __restrict__ out, int n) {
    int node = blockIdx.x * 4 + (threadIdx.x >> 6);
    int lane = threadIdx.x & 63;
    if (node >= n) return;
    int p = lane & 31, hf = lane >> 5;
    float dis_c = dis[node];
    float A0, A1;
    gather_node(node, lane, p, hf, dis_c, ptr, edg, hbf, A0, A1);
    float2 bv = ((const float2*)b)[p];
    float2 wv = ((const float2*)Wf)[p];
    float x0 = fmaxf(dis_c * A0 + bv.x, 0.f);
    float x1 = fmaxf(dis_c * A1 + bv.y, 0.f);
    float v = x0 * wv.x + x1 * wv.y;             // valid in lanes 0..31
#pragma unroll
    for (int off = 16; off > 0; off >>= 1) v += __shfl_down(v, off);
    if (lane == 0) out[node] = v + bf[0];
}

extern "C" void kernel_launch(void* const* d_in, const int* in_sizes, int n_in,
                              void* d_out, int out_size, void* d_ws, size_t ws_size,
                              hipStream_t stream) {
    const float* x0 = (const float*)d_in[0];
    const int*   ei = (const int*)d_in[1];
    const float* ew = (const float*)d_in[2];
    const float* Ws = (const float*)d_in[3];
    const float* bs = (const float*)d_in[4];
    const float* Wf = (const float*)d_in[5];
    const float* bf = (const float*)d_in[6];

    const int n = in_sizes[0] / DCH;
    const int e = in_sizes[2];
    const int L = in_sizes[3] / (DCH * DCH);     // = 3

    const int* row = ei;        // edge_index[0] = source (gathered)
    const int* col = ei + e;    // edge_index[1] = target (aggregated)

    size_t off = 0;
    auto alloc = [&](size_t bytes) {
        off = (off + 255) & ~(size_t)255;
        void* r = (char*)d_ws + off;
        off += bytes;
        return r;
    };
    const int nb_scan = (n + 1023) / 1024;       // must be <= 64
    int*   cnt  = (int*)  alloc((size_t)n * 4);
    int*   ptr  = (int*)  alloc((size_t)(n + 1) * 4);
    int*   bsum = (int*)  alloc((size_t)(nb_scan + 1) * 4);
    float* dis  = (float*)alloc((size_t)n * 4);
    short* wpk  = (short*)alloc((size_t)L * 2 * 512 * 8 * 2);
    uint2* edg  = (uint2*)alloc((size_t)e * 8);
    unsigned char* lrank = (unsigned char*)alloc((size_t)e);
    // region A: hist (NB_CSR*n u8) aliases TWO bf16 h buffers (2*n*64*2 bytes);
    // hist is dead after place_k, which precedes the first gemm write.
    size_t szA = (size_t)NB_CSR * n;
    size_t szH = (size_t)2 * n * DCH * 2;
    unsigned char* hist = (unsigned char*)alloc(szA > szH ? szA : szH);
    unsigned short* hb_a = (unsigned short*)hist;
    unsigned short* hb_b = hb_a + (size_t)n * DCH;

    dim3 blk(256);
    const int n_tiles = (n + 15) / 16;

    // ---- CSR build + norm + W pack ----
    histrank_k<<<dim3(NB_CSR), dim3(1024), 0, stream>>>(col, hist, lrank, n, e);
    hist2_k   <<<dim3((n / 4 + 1 + 255) / 256), blk, 0, stream>>>(hist, cnt, n);
    scan1_k   <<<dim3(nb_scan), dim3(1024), 0, stream>>>(cnt, ptr, bsum, n);
    scan2_k   <<<dim3(1), dim3(64), 0, stream>>>(bsum, nb_scan);
    scan3_k   <<<dim3(nb_scan), dim3(1024), 0, stream>>>(ptr, bsum, n, nb_scan);
    place_k   <<<dim3(NB_CSR), dim3(1024), 0, stream>>>(row, col, ew, ptr, hist, lrank, edg, n, e);
    deg_k     <<<dim3((n + 3) / 4), blk, 0, stream>>>(ptr, edg, dis, n);
    normw_k   <<<dim3((e + 255) / 256), blk, 0, stream>>>(edg, dis, e);
    pack_k    <<<dim3((L * 512 + 255) / 256), blk, 0, stream>>>(Ws, wpk, L);

    // ---- layers (fused) ----
    const size_t wstride = (size_t)2 * 512 * 8;
    gemm_k<<<dim3((n_tiles + 3) / 4), blk, 0, stream>>>(x0, wpk, hb_a, n_tiles);
    gg_k  <<<dim3(n_tiles), blk, 0, stream>>>(ptr, edg, dis, (const unsigned*)hb_a,
                                              bs, wpk + wstride, hb_b, n);
    gg_k  <<<dim3(n_tiles), blk, 0, stream>>>(ptr, edg, dis, (const unsigned*)hb_b,
                                              bs + DCH, wpk + 2 * wstride, hb_a, n);
    gf_k  <<<dim3((n + 3) / 4), blk, 0, stream>>>(ptr, edg, dis, (const unsigned*)hb_a,
                                                  bs + 2 * DCH, Wf, bf, (float*)d_out, n);
}

// Round 11
// 223.751 us; speedup vs baseline: 1.1890x; 1.1385x over previous
//
#include <hip/hip_runtime.h>
#include <hip/hip_bf16.h>

#define DCH 64
#define NB_CSR 256          // edge-chunk blocks; chunk = ceil(e/256)
#define MAXBINS 256         // bins = ceil(n/256); n<=65536

typedef __attribute__((ext_vector_type(8))) short bfrag;   // 8 bf16
typedef __attribute__((ext_vector_type(4))) float ffrag;   // 4 fp32

static __device__ __forceinline__ unsigned short f2bf(float f) {
    unsigned u = __float_as_uint(f);
    unsigned r = (u + 0x7fffu + ((u >> 16) & 1u)) >> 16;   // RNE
    return (unsigned short)r;
}
static __device__ __forceinline__ float bf2f(unsigned short s) {
    return __uint_as_float(((unsigned)s) << 16);
}

// ---- CSR pass 1: per-block bin counts (bin = col>>8) ----
__global__ __launch_bounds__(1024) void binc_k(const int* __restrict__ col,
                                               unsigned* __restrict__ blkcnt, int e) {
    __shared__ unsigned bins[MAXBINS];
    int B = blockIdx.x, tid = threadIdx.x;
    int chunk = (e + NB_CSR - 1) / NB_CSR;
    int beg = B * chunk, end = min(e, beg + chunk);
    if (tid < MAXBINS) bins[tid] = 0;
    __syncthreads();
    for (int i = beg + tid; i < end; i += 1024)
        atomicAdd(&bins[col[i] >> 8], 1u);
    __syncthreads();
    if (tid < MAXBINS) blkcnt[B * MAXBINS + tid] = bins[tid];
}

// ---- CSR pass 2 (1 block): bin bases + per-(block,bin) cursors ----
__global__ __launch_bounds__(256) void bincur_k(const unsigned* __restrict__ blkcnt,
                                                unsigned* __restrict__ blkcur,
                                                int* __restrict__ binbase,
                                                int* __restrict__ ptr,
                                                int nbins, int n, int e) {
    __shared__ unsigned tot[MAXBINS];
    __shared__ unsigned base[MAXBINS + 1];
    int j = threadIdx.x;
    unsigned t = 0;
    if (j < nbins) {
        for (int B = 0; B < NB_CSR; B += 8) {      // 8-deep MLP column sum
            t += blkcnt[(B + 0) * MAXBINS + j] + blkcnt[(B + 1) * MAXBINS + j]
               + blkcnt[(B + 2) * MAXBINS + j] + blkcnt[(B + 3) * MAXBINS + j]
               + blkcnt[(B + 4) * MAXBINS + j] + blkcnt[(B + 5) * MAXBINS + j]
               + blkcnt[(B + 6) * MAXBINS + j] + blkcnt[(B + 7) * MAXBINS + j];
        }
    }
    tot[j] = t;
    __syncthreads();
    if (j == 0) {
        unsigned run = 0;
        for (int k = 0; k < nbins; ++k) { base[k] = run; run += tot[k]; }
        base[nbins] = run;
    }
    __syncthreads();
    if (j < nbins) {
        unsigned run = base[j];
        binbase[j] = (int)run;
        for (int B = 0; B < NB_CSR; B += 4) {      // 4-deep MLP walk
            unsigned c0 = blkcnt[(B + 0) * MAXBINS + j];
            unsigned c1 = blkcnt[(B + 1) * MAXBINS + j];
            unsigned c2 = blkcnt[(B + 2) * MAXBINS + j];
            unsigned c3 = blkcnt[(B + 3) * MAXBINS + j];
            blkcur[(B + 0) * MAXBINS + j] = run;  run += c0;
            blkcur[(B + 1) * MAXBINS + j] = run;  run += c1;
            blkcur[(B + 2) * MAXBINS + j] = run;  run += c2;
            blkcur[(B + 3) * MAXBINS + j] = run;  run += c3;
        }
    }
    if (j == 0) { binbase[nbins] = e; ptr[n] = e; }
}

// ---- CSR pass 3: scatter packed records to bins (runs at block cursors) ----
__global__ __launch_bounds__(1024) void binfill_k(const int* __restrict__ row,
                                                  const int* __restrict__ col,
                                                  const float* __restrict__ ew,
                                                  const unsigned* __restrict__ blkcur,
                                                  uint2* __restrict__ rec, int e) {
    __shared__ unsigned cur[MAXBINS];
    int B = blockIdx.x, tid = threadIdx.x;
    int chunk = (e + NB_CSR - 1) / NB_CSR;
    int beg = B * chunk, end = min(e, beg + chunk);
    if (tid < MAXBINS) cur[tid] = blkcur[B * MAXBINS + tid];
    __syncthreads();
    for (int i = beg + tid; i < end; i += 1024) {
        int c = col[i];
        unsigned slot = atomicAdd(&cur[c >> 8], 1u);
        rec[slot] = make_uint2((unsigned)row[i] | ((unsigned)(c & 255) << 20),
                               __float_as_uint(ew[i]));
    }
}

// ---- CSR pass 4 (1 block per bin): node hist + ptr slice + fused deg/dis +
//      final placement into the bin's contiguous edg window (L2-local) ----
__global__ __launch_bounds__(1024) void csr_k(const uint2* __restrict__ rec,
                                              const int* __restrict__ binbase,
                                              int* __restrict__ ptr,
                                              uint2* __restrict__ edg,
                                              float* __restrict__ dis, int n) {
    __shared__ unsigned ncnt[256];
    __shared__ unsigned nbase[256];
    __shared__ float degs[256];
    int b = blockIdx.x, tid = threadIdx.x;
    int beg = binbase[b], end = binbase[b + 1];
    int node0 = b << 8;
    int nn = min(256, n - node0);
    if (tid < 256) { ncnt[tid] = 0; degs[tid] = 0.f; }
    __syncthreads();
    for (int i = beg + tid; i < end; i += 1024) {
        uint2 r = rec[i];
        unsigned c8 = r.x >> 20;
        atomicAdd(&ncnt[c8], 1u);
        atomicAdd(&degs[c8], __uint_as_float(r.y));
    }
    __syncthreads();
    if (tid == 0) {
        unsigned run = (unsigned)beg;
        for (int k = 0; k < 256; ++k) { nbase[k] = run; run += ncnt[k]; }
    }
    __syncthreads();
    if (tid < nn) {
        ptr[node0 + tid] = (int)nbase[tid];
        dis[node0 + tid] = rsqrtf(degs[tid] + 2.0f);
    }
    if (tid < 256) ncnt[tid] = 0;
    __syncthreads();
    for (int i = beg + tid; i < end; i += 1024) {
        uint2 r = rec[i];
        unsigned c8 = r.x >> 20;
        unsigned pos = nbase[c8] + atomicAdd(&ncnt[c8], 1u);
        edg[pos] = make_uint2(r.x & 0xFFFFFu, r.y);
    }
}

// edg.y <- w * dis[src]  (fold source-side norm in once, for all layers)
__global__ __launch_bounds__(256) void normw_k(uint2* __restrict__ edg,
                                               const float* __restrict__ dis, int e) {
    int i = blockIdx.x * 256 + threadIdx.x;
    if (i >= e) return;
    uint2 ev = edg[i];
    ((unsigned*)edg)[2 * i + 1] =
        __float_as_uint(__uint_as_float(ev.y) * dis[ev.x]);
}

// Pack W (all L layers) into MFMA B-fragment layout, bf16 hi/lo split.
__global__ __launch_bounds__(256) void pack_k(const float* __restrict__ Ws,
                                              short* __restrict__ wpk, int L) {
    int ent = blockIdx.x * 256 + threadIdx.x;
    if (ent >= L * 512) return;
    int layer = ent >> 9;
    int r = ent & 511;
    int lane = r & 63;
    int st = r >> 6;
    int s = st >> 2, t = st & 3;
    int quad = lane >> 4;
    int ncol = t * 16 + (lane & 15);
    const float* W = Ws + (size_t)layer * DCH * DCH;
    union { short sh[8]; int4 v; } hi, lo;
#pragma unroll
    for (int j = 0; j < 8; ++j) {
        int k = s * 32 + quad * 8 + j;
        float w = W[k * DCH + ncol];
        unsigned short h = f2bf(w);
        hi.sh[j] = (short)h;
        lo.sh[j] = (short)f2bf(w - bf2f(h));
    }
    *(int4*)(wpk + ((size_t)(layer * 2 + 0) * 512 + r) * 8) = hi.v;
    *(int4*)(wpk + ((size_t)(layer * 2 + 1) * 512 + r) * 8) = lo.v;
}

// layer-0 GEMM: h = x0 @ W0 via bf16-split MFMA; output bf16.
__global__ __launch_bounds__(256) void gemm_k(const float* __restrict__ x,
                                              const short* __restrict__ wpk_layer,
                                              unsigned short* __restrict__ hb, int n_tiles) {
    __shared__ short Wl[2][512 * 8];
    {
        const int4* src = (const int4*)wpk_layer;
        int4* dst = (int4*)&Wl[0][0];
        for (int i = threadIdx.x; i < 1024; i += 256) dst[i] = src[i];
    }
    __syncthreads();
    int wave = threadIdx.x >> 6, lane = threadIdx.x & 63;
    int tile = blockIdx.x * 4 + wave;
    if (tile >= n_tiles) return;
    int m = lane & 15, quad = lane >> 4;
    int row = tile * 16 + m;

    float av[2][8];
    {
        const float4* p0 = (const float4*)(x + (size_t)row * DCH + quad * 8);
        const float4* p1 = (const float4*)(x + (size_t)row * DCH + 32 + quad * 8);
        float4 a0 = p0[0], a1 = p0[1], b0 = p1[0], b1 = p1[1];
        av[0][0] = a0.x; av[0][1] = a0.y; av[0][2] = a0.z; av[0][3] = a0.w;
        av[0][4] = a1.x; av[0][5] = a1.y; av[0][6] = a1.z; av[0][7] = a1.w;
        av[1][0] = b0.x; av[1][1] = b0.y; av[1][2] = b0.z; av[1][3] = b0.w;
        av[1][4] = b1.x; av[1][5] = b1.y; av[1][6] = b1.z; av[1][7] = b1.w;
    }
    bfrag ah[2], al[2];
#pragma unroll
    for (int s = 0; s < 2; ++s)
#pragma unroll
        for (int j = 0; j < 8; ++j) {
            unsigned short hbv = f2bf(av[s][j]);
            ah[s][j] = (short)hbv;
            al[s][j] = (short)f2bf(av[s][j] - bf2f(hbv));
        }

#pragma unroll
    for (int t = 0; t < 4; ++t) {
        ffrag acc = {0.f, 0.f, 0.f, 0.f};
#pragma unroll
        for (int s = 0; s < 2; ++s) {
            bfrag wh = *(bfrag*)&Wl[0][((s * 4 + t) * 64 + lane) * 8];
            bfrag wl = *(bfrag*)&Wl[1][((s * 4 + t) * 64 + lane) * 8];
            acc = __builtin_amdgcn_mfma_f32_16x16x32_bf16(ah[s], wh, acc, 0, 0, 0);
            acc = __builtin_amdgcn_mfma_f32_16x16x32_bf16(al[s], wh, acc, 0, 0, 0);
            acc = __builtin_amdgcn_mfma_f32_16x16x32_bf16(ah[s], wl, acc, 0, 0, 0);
        }
        int colc = t * 16 + m;
#pragma unroll
        for (int r = 0; r < 4; ++r)
            hb[(size_t)(tile * 16 + quad * 4 + r) * DCH + colc] = f2bf(acc[r]);
    }
}

// gather core: lane = channel pair, 2 edges/step, 8-deep pipelined.
// 8 outstanding 4B loads per lane — max MLP for this latency-bound loop.
static __device__ __forceinline__ void gather_node(int node, int lane, int p, int hf,
                                                   float dis_c,
                                                   const int* __restrict__ ptr,
                                                   const uint2* __restrict__ edg,
                                                   const unsigned* __restrict__ hbf,
                                                   float& A0, float& A1) {
    float a0 = 0.f, a1 = 0.f;
    if (hf == 0) {                               // self-loop term
        unsigned sv = hbf[(size_t)node * 32 + p];
        a0 = 2.0f * dis_c * __uint_as_float(sv << 16);
        a1 = 2.0f * dis_c * __uint_as_float(sv & 0xffff0000u);
    }
    int beg = ptr[node], end = ptr[node + 1];
    for (int base = beg; base < end; base += 64) {
        int idx = base + lane;
        int rv = 0; float nv = 0.f;
        if (idx < end) {
            uint2 ev = edg[idx];
            rv = (int)ev.x;
            nv = __uint_as_float(ev.y);          // pre-folded w * dis[src]
        }
        int m = min(64, end - base);
        int steps = (((m + 1) >> 1) + 7) & ~7;   // 2 edges/step, 8-deep pipelined
        for (int j0 = 0; j0 < steps; j0 += 8) {
            unsigned hv[8]; float nn[8];
#pragma unroll
            for (int q = 0; q < 8; ++q) {
                int eidx = 2 * (j0 + q) + hf;
                int r = __shfl(rv, eidx);
                nn[q] = __shfl(nv, eidx);
                hv[q] = hbf[(size_t)r * 32 + p];
            }
#pragma unroll
            for (int q = 0; q < 8; ++q) {
                a0 += __uint_as_float(hv[q] << 16) * nn[q];
                a1 += __uint_as_float(hv[q] & 0xffff0000u) * nn[q];
            }
        }
    }
    A0 = a0 + __shfl_xor(a0, 32);
    A1 = a1 + __shfl_xor(a1, 32);
}

// fused gather(l) + gemm(l+1): block = 4 waves = 16 nodes; activation tile in
// LDS (stride 68: 16B-aligned rows); wave t does MFMA col-group t.
__global__ __launch_bounds__(256) void gg_k(const int* __restrict__ ptr,
                                            const uint2* __restrict__ edg,
                                            const float* __restrict__ dis,
                                            const unsigned* __restrict__ hbf,
                                            const float* __restrict__ b,
                                            const short* __restrict__ wpk_next,
                                            unsigned short* __restrict__ hb_out, int n) {
    __shared__ float xs[16][68];
    int w = threadIdx.x >> 6, lane = threadIdx.x & 63;
    int p = lane & 31, hf = lane >> 5;
    int tile = blockIdx.x;
    float2 bv = ((const float2*)b)[p];
#pragma unroll 1
    for (int i = 0; i < 4; ++i) {
        int node = tile * 16 + w * 4 + i;
        if (node < n) {
            float dis_c = dis[node];
            float A0, A1;
            gather_node(node, lane, p, hf, dis_c, ptr, edg, hbf, A0, A1);
            if (hf == 0) {
                xs[w * 4 + i][2 * p]     = fmaxf(dis_c * A0 + bv.x, 0.f);
                xs[w * 4 + i][2 * p + 1] = fmaxf(dis_c * A1 + bv.y, 0.f);
            }
        }
    }
    __syncthreads();
    // ---- GEMM phase: wave w = output col-group t ----
    int m = lane & 15, quad = lane >> 4, t = w;
    bfrag ah[2], al[2];
#pragma unroll
    for (int s = 0; s < 2; ++s)
#pragma unroll
        for (int j = 0; j < 8; ++j) {
            float v = xs[m][s * 32 + quad * 8 + j];
            unsigned short hbv = f2bf(v);
            ah[s][j] = (short)hbv;
            al[s][j] = (short)f2bf(v - bf2f(hbv));
        }
    ffrag acc = {0.f, 0.f, 0.f, 0.f};
#pragma unroll
    for (int s = 0; s < 2; ++s) {
        bfrag wh = *(const bfrag*)(wpk_next + ((size_t)((s * 4 + t) * 64 + lane)) * 8);
        bfrag wl = *(const bfrag*)(wpk_next + ((size_t)(512 + (s * 4 + t) * 64 + lane)) * 8);
        acc = __builtin_amdgcn_mfma_f32_16x16x32_bf16(ah[s], wh, acc, 0, 0, 0);
        acc = __builtin_amdgcn_mfma_f32_16x16x32_bf16(al[s], wh, acc, 0, 0, 0);
        acc = __builtin_amdgcn_mfma_f32_16x16x32_bf16(ah[s], wl, acc, 0, 0, 0);
    }
    int colc = t * 16 + m;
#pragma unroll
    for (int r = 0; r < 4; ++r) {
        int orow = tile * 16 + quad * 4 + r;
        if (orow < n) hb_out[(size_t)orow * DCH + colc] = f2bf(acc[r]);
    }
}

// fused gather(last) + final dot: out[node] = relu-agg(node) . Wf + bf
__global__ __launch_bounds__(256) void gf_k(const int* __restrict__ ptr,
                                            const uint2* __restrict__ edg,
                                            const float* __restrict__ dis,
                                            const unsigned* __restrict__ hbf,
                                            const float* __restrict__ b,
                                            const float* __restrict__ Wf,
                                            const float* __restrict__ bf,
                                            float* __restrict__ out, int n) {
    int node = blockIdx.x * 4 + (threadIdx.x >> 6);
    int lane = threadIdx.x & 63;
    if (node >= n) return;
    int p = lane & 31, hf = lane >> 5;
    float dis_c = dis[node];
    float A0, A1;
    gather_node(node, lane, p, hf, dis_c, ptr, edg, hbf, A0, A1);
    float2 bv = ((const float2*)b)[p];
    float2 wv = ((const float2*)Wf)[p];
    float x0 = fmaxf(dis_c * A0 + bv.x, 0.f);
    float x1 = fmaxf(dis_c * A1 + bv.y, 0.f);
    float v = x0 * wv.x + x1 * wv.y;             // valid in lanes 0..31
#pragma unroll
    for (int off = 16; off > 0; off >>= 1) v += __shfl_down(v, off);
    if (lane == 0) out[node] = v + bf[0];
}

extern "C" void kernel_launch(void* const* d_in, const int* in_sizes, int n_in,
                              void* d_out, int out_size, void* d_ws, size_t ws_size,
                              hipStream_t stream) {
    const float* x0 = (const float*)d_in[0];
    const int*   ei = (const int*)d_in[1];
    const float* ew = (const float*)d_in[2];
    const float* Ws = (const float*)d_in[3];
    const float* bs = (const float*)d_in[4];
    const float* Wf = (const float*)d_in[5];
    const float* bf = (const float*)d_in[6];

    const int n = in_sizes[0] / DCH;
    const int e = in_sizes[2];
    const int L = in_sizes[3] / (DCH * DCH);     // = 3

    const int* row = ei;        // edge_index[0] = source (gathered)
    const int* col = ei + e;    // edge_index[1] = target (aggregated)
    const int nbins = (n + 255) >> 8;            // 196 for n=50000 (must be <= 256)

    size_t off = 0;
    auto alloc = [&](size_t bytes) {
        off = (off + 255) & ~(size_t)255;
        void* r = (char*)d_ws + off;
        off += bytes;
        return r;
    };
    int*      ptr     = (int*)     alloc((size_t)(n + 1) * 4);
    float*    dis     = (float*)   alloc((size_t)n * 4);
    short*    wpk     = (short*)   alloc((size_t)L * 2 * 512 * 8 * 2);
    uint2*    edg     = (uint2*)   alloc((size_t)e * 8);
    unsigned* blkcnt  = (unsigned*)alloc((size_t)NB_CSR * MAXBINS * 4);
    unsigned* blkcur  = (unsigned*)alloc((size_t)NB_CSR * MAXBINS * 4);
    int*      binbase = (int*)     alloc((size_t)(MAXBINS + 1) * 4);
    // region A: rec (e uint2 = 10 MB) aliases TWO bf16 h buffers (12.8 MB);
    // rec is dead after csr_k, which precedes the first gemm write.
    size_t szR = (size_t)e * 8;
    size_t szH = (size_t)2 * n * DCH * 2;
    unsigned char* regA = (unsigned char*)alloc(szR > szH ? szR : szH);
    uint2* rec = (uint2*)regA;
    unsigned short* hb_a = (unsigned short*)regA;
    unsigned short* hb_b = hb_a + (size_t)n * DCH;

    dim3 blk(256);
    const int n_tiles = (n + 15) / 16;

    // ---- CSR build (bin sort) + norm + W pack ----
    binc_k   <<<dim3(NB_CSR), dim3(1024), 0, stream>>>(col, blkcnt, e);
    bincur_k <<<dim3(1), blk, 0, stream>>>(blkcnt, blkcur, binbase, ptr, nbins, n, e);
    binfill_k<<<dim3(NB_CSR), dim3(1024), 0, stream>>>(row, col, ew, blkcur, rec, e);
    csr_k    <<<dim3(nbins), dim3(1024), 0, stream>>>(rec, binbase, ptr, edg, dis, n);
    normw_k  <<<dim3((e + 255) / 256), blk, 0, stream>>>(edg, dis, e);
    pack_k   <<<dim3((L * 512 + 255) / 256), blk, 0, stream>>>(Ws, wpk, L);

    // ---- layers (fused) ----
    const size_t wstride = (size_t)2 * 512 * 8;
    gemm_k<<<dim3((n_tiles + 3) / 4), blk, 0, stream>>>(x0, wpk, hb_a, n_tiles);
    gg_k  <<<dim3(n_tiles), blk, 0, stream>>>(ptr, edg, dis, (const unsigned*)hb_a,
                                              bs, wpk + wstride, hb_b, n);
    gg_k  <<<dim3(n_tiles), blk, 0, stream>>>(ptr, edg, dis, (const unsigned*)hb_b,
                                              bs + DCH, wpk + 2 * wstride, hb_a, n);
    gf_k  <<<dim3((n + 3) / 4), blk, 0, stream>>>(ptr, edg, dis, (const unsigned*)hb_a,
                                                  bs + 2 * DCH, Wf, bf, (float*)d_out, n);
}